// Round 14
// baseline (953.451 us; speedup 1.0000x reference)
//
#include <hip/hip_runtime.h>
#include <hip/hip_bf16.h>

#define M_DIM 8192
#define K_DIM 4096
#define N4    8192
#define N8    2816
#define NT    11008   // 43 * 256
#define TM    (M_DIM / 256)   // 32
#define TN    (NT / 256)      // 43
#define NKT   (K_DIM / 64)    // 64 K-tiles
#define NFULL 1280            // 5 * 256 full-tile blocks
#define GRID  1472            // 1280 full + 192 half (96 tiles split in M)

typedef __attribute__((ext_vector_type(4))) float  f32x4;
typedef __attribute__((ext_vector_type(4))) float  float4v;
typedef __attribute__((ext_vector_type(8))) __bf16 bf16x8;
typedef __attribute__((ext_vector_type(4))) unsigned short ushort4v;
typedef __attribute__((ext_vector_type(8))) unsigned short ushort8v;

__device__ __forceinline__ unsigned short f2bf(float f) {
  union { float f; unsigned int u; } v; v.f = f;
  unsigned int u = v.u;
  unsigned int r = u + 0x7FFFu + ((u >> 16) & 1u);   // RNE
  return (unsigned short)(r >> 16);
}

// ---- x fp32 -> bf16, contiguous ----
__global__ void conv_x_kernel(const float* __restrict__ x,
                              unsigned short* __restrict__ xb, int n8) {
  int idx = blockIdx.x * blockDim.x + threadIdx.x;
  int stride = gridDim.x * blockDim.x;
  for (int i = idx; i < n8; i += stride) {
    const float4v* src = (const float4v*)(x + (size_t)i * 8);
    float4v a = src[0], b = src[1];
    ushort8v o;
    o[0] = f2bf(a[0]); o[1] = f2bf(a[1]); o[2] = f2bf(a[2]); o[3] = f2bf(a[3]);
    o[4] = f2bf(b[0]); o[5] = f2bf(b[1]); o[6] = f2bf(b[2]); o[7] = f2bf(b[3]);
    ((ushort8v*)xb)[i] = o;
  }
}

// ---- W2 fragment-linear permuted weights ----
// 16B chunk index: ci = ((T*64 + u)*8 + n*2 + kk)*64 + (g<<4) + (r&15)
//   T = tile_n*4 + wcn; data = B_perm[r][u*64 + kk*32 + g*8 .. +8)
// GEMM reads: lane l of wave (T) gets chunk (g=l>>4, r&15=l&15) == MFMA B-frag.
__global__ void conv_w2_kernel(const float* __restrict__ w4,
                               const float* __restrict__ w8,
                               const int* __restrict__ inv_perm,
                               unsigned short* __restrict__ w2) {
  int task = blockIdx.x * 4 + (threadIdx.x >> 6);   // 0..11007 = 688 rg * 16 uq
  int lane = threadIdx.x & 63;
  int rg = task >> 4;          // 0..687
  int uq = task & 15;          // 0..15
  int r  = rg * 16 + (lane & 15);
  int u  = uq * 4 + (lane >> 4);
  int pr = inv_perm[r];
  const float* src = (pr < N4) ? (w4 + (size_t)pr * K_DIM)
                               : (w8 + (size_t)(pr - N4) * K_DIM);
  float4v v[16];
#pragma unroll
  for (int i = 0; i < 16; ++i) v[i] = *(const float4v*)(src + u * 64 + i * 4);

  const int T = rg >> 2;       // tile_n*4 + wcn
  const int n = rg & 3;
  const size_t cbase = (((size_t)T * 64 + u) * 8 + n * 2) * 64 + (lane & 15);
#pragma unroll
  for (int kk = 0; kk < 2; ++kk) {
#pragma unroll
    for (int g = 0; g < 4; ++g) {
      float4v lo = v[kk * 8 + g * 2], hi = v[kk * 8 + g * 2 + 1];
      ushort8v o;
      o[0] = f2bf(lo[0]); o[1] = f2bf(lo[1]); o[2] = f2bf(lo[2]); o[3] = f2bf(lo[3]);
      o[4] = f2bf(hi[0]); o[5] = f2bf(hi[1]); o[6] = f2bf(hi[2]); o[7] = f2bf(hi[3]);
      size_t ci = cbase + (size_t)kk * 64 + (g << 4);
      *(ushort8v*)(w2 + ci * 8) = o;
    }
  }
}

// ============== 256x256 bf16 GEMM: A in LDS, B from global regs ============
// out[m][n] = sum_k A[m][k]*B[n][k] + bias[n]
// 8 waves 2M x 4N; wave out 128x64. LDS = A only: 2 x 32 KiB double buffer.
// B: plain vector loads from W2 (read-only -> compiler-managed vmcnt, safe).
// ONE manual vmcnt(0)+barrier per K-tile (certifies A stages for next tile).
// Buffer safety: reads of buf X in iter u retire via lgkm(0) mid-iter, before
// the end barrier; stages into X happen in iter u+1 after that barrier.
__global__ __launch_bounds__(512, 2)
void gemm256_kernel(const unsigned short* __restrict__ A,
                    const unsigned short* __restrict__ Bw2,
                    const float* __restrict__ bias,
                    float* __restrict__ C) {
  __shared__ __align__(16) unsigned short lds[2 * 16384];  // 64 KiB (A only)

  int bid = blockIdx.x;
  int vbid, mhalf, is_half;
  if (bid < NFULL) { vbid = bid; mhalf = 0; is_half = 0; }
  else { int h = bid - NFULL; vbid = NFULL + (h >> 1); mhalf = h & 1; is_half = 1; }
  int wgid = (vbid & 7) * ((TM * TN) / 8) + (vbid >> 3);  // bijective, 1376%8==0
  int tile_m = wgid / TN;
  int tile_n = wgid % TN;

  const int tid  = threadIdx.x;
  const int wid  = tid >> 6;
  const int lane = tid & 63;
  const int wr  = wid >> 2;         // 0..1
  const int wcn = wid & 3;          // 0..3
  const int l15 = lane & 15;
  const int rswz  = (lane & 7) << 4;
  const int coff0 = (((lane >> 4) * 16) + 0)  ^ rswz;
  const int coff1 = (((lane >> 4) * 16) + 64) ^ rswz;
  const int st_row8 = lane >> 3;
  const int st_scol = ((lane & 7) * 16) ^ ((lane & 0x38) << 1);
  const int dstoff  = wid * 512;

  // per-lane W2 base: chunk = T*32768 + u*512 + f*64 + lane  (x8 elems each)
  const unsigned short* w2lane =
      Bw2 + ((size_t)(tile_n * 4 + wcn) * 32768 + (size_t)lane) * 8;

  auto stage = [&](const unsigned short* __restrict__ srcb,
                   unsigned short* ltile, int q, int ktelem) {
    __builtin_amdgcn_global_load_lds(
        (const __attribute__((address_space(1))) void*)(srcb + q * (64 * K_DIM) + ktelem),
        (__attribute__((address_space(3))) void*)(ltile + q * 4096 + dstoff), 16, 0, 0);
  };
  auto fragld = [&](const unsigned short* ltile, int row, int coff) -> bf16x8 {
    return *(const bf16x8*)((const char*)ltile + row * 128 + coff);
  };

  if (is_half) {
    // ============ half-tile path (128x256): A 2x16KiB LDS, B from global ====
    const unsigned short* aSh =
        A + ((size_t)tile_m * 256 + (size_t)mhalf * 128 + (size_t)(wid * 8 + st_row8)) * K_DIM
          + (st_scol >> 1);
    f32x4 acch[4][4];
#pragma unroll
    for (int i = 0; i < 4; ++i)
#pragma unroll
      for (int j = 0; j < 4; ++j) acch[i][j] = (f32x4){0.f, 0.f, 0.f, 0.f};

    stage(aSh, lds + 0, 0, 0); stage(aSh, lds + 0, 1, 0);
    asm volatile("s_waitcnt vmcnt(0)" ::: "memory");
    __builtin_amdgcn_s_barrier();

#pragma unroll 1
    for (int u = 0; u < NKT; ++u) {
      unsigned short* Ac = lds + (u & 1) * 8192;
      unsigned short* An = lds + (8192 - (u & 1) * 8192);
      const unsigned short* wB = w2lane + (size_t)u * 4096;
      bf16x8 bh[4][2];
#pragma unroll
      for (int n = 0; n < 4; ++n) {
        bh[n][0] = *(const bf16x8*)(wB + (n * 2) * 512);
        bh[n][1] = *(const bf16x8*)(wB + (n * 2 + 1) * 512);
      }
      int kn = ((u + 1 < NKT) ? (u + 1) : (NKT - 1)) * 64;
      stage(aSh, An, 0, kn); stage(aSh, An, 1, kn);
      bf16x8 ah[4][2];
#pragma unroll
      for (int m = 0; m < 4; ++m) {
        int row = wr * 64 + m * 16 + l15;
        ah[m][0] = fragld(Ac, row, coff0);
        ah[m][1] = fragld(Ac, row, coff1);
      }
      asm volatile("s_waitcnt lgkmcnt(0)" ::: "memory");
      __builtin_amdgcn_sched_barrier(0);
      __builtin_amdgcn_s_setprio(1);
#pragma unroll
      for (int m = 0; m < 4; ++m)
#pragma unroll
        for (int n = 0; n < 4; ++n) {
          acch[m][n] = __builtin_amdgcn_mfma_f32_16x16x32_bf16(ah[m][0], bh[n][0], acch[m][n], 0, 0, 0);
          acch[m][n] = __builtin_amdgcn_mfma_f32_16x16x32_bf16(ah[m][1], bh[n][1], acch[m][n], 0, 0, 0);
        }
      __builtin_amdgcn_s_setprio(0);
      asm volatile("s_waitcnt vmcnt(0)" ::: "memory");
      __builtin_amdgcn_s_barrier();
    }

#pragma unroll
    for (int n = 0; n < 4; ++n) {
      int col = tile_n * 256 + wcn * 64 + n * 16 + l15;
      float bv = bias[col];
#pragma unroll
      for (int m = 0; m < 4; ++m) {
        int row0 = tile_m * 256 + mhalf * 128 + wr * 64 + m * 16 + ((lane >> 4) * 4);
#pragma unroll
        for (int r = 0; r < 4; ++r) {
          C[(size_t)(row0 + r) * NT + col] = acch[m][n][r] + bv;
        }
      }
    }
    return;
  }

  // ====================== full-tile path ====================================
  const unsigned short* aS =
      A + ((size_t)tile_m * 256 + (size_t)(wid * 8 + st_row8)) * K_DIM + (st_scol >> 1);

  f32x4 acc[8][4];
#pragma unroll
  for (int i = 0; i < 8; ++i)
#pragma unroll
    for (int j = 0; j < 4; ++j) acc[i][j] = (f32x4){0.f, 0.f, 0.f, 0.f};

  // ---- prologue: stage tile0 A-units (4); drain; barrier.
  stage(aS, lds + 0, 0, 0); stage(aS, lds + 0, 1, 0);
  stage(aS, lds + 0, 2, 0); stage(aS, lds + 0, 3, 0);
  asm volatile("s_waitcnt vmcnt(0)" ::: "memory");
  __builtin_amdgcn_s_barrier();

#define CLUSTER(MB, AF)                                                       \
    _Pragma("unroll")                                                         \
    for (int m = 0; m < 4; ++m)                                               \
      _Pragma("unroll")                                                       \
      for (int n = 0; n < 4; ++n) {                                           \
        acc[(MB)+m][n] = __builtin_amdgcn_mfma_f32_16x16x32_bf16(AF[m][0], bh[n][0], acc[(MB)+m][n], 0, 0, 0); \
        acc[(MB)+m][n] = __builtin_amdgcn_mfma_f32_16x16x32_bf16(AF[m][1], bh[n][1], acc[(MB)+m][n], 0, 0, 0); \
      }

#define KITER(AC, AN, UB, KN1E)                                               \
  {                                                                           \
    unsigned short* const Ac = (AC);                                          \
    unsigned short* const An = (AN);                                          \
    const unsigned short* wB = w2lane + (size_t)(UB) * 4096;                  \
    bf16x8 bh[4][2];                                                          \
    _Pragma("unroll")                                                         \
    for (int n = 0; n < 4; ++n) {                                             \
      bh[n][0] = *(const bf16x8*)(wB + (n * 2) * 512);                        \
      bh[n][1] = *(const bf16x8*)(wB + (n * 2 + 1) * 512);                    \
    }                                                                         \
    bf16x8 a0[4][2], a1[4][2];                                                \
    _Pragma("unroll")                                                         \
    for (int m = 0; m < 4; ++m) {                                             \
      int row = wr * 128 + m * 16 + l15;                                      \
      a0[m][0] = fragld(Ac, row, coff0);                                      \
      a0[m][1] = fragld(Ac, row, coff1);                                      \
    }                                                                         \
    __builtin_amdgcn_sched_barrier(0);                                        \
    _Pragma("unroll")                                                         \
    for (int m = 0; m < 4; ++m) {                                             \
      int row = wr * 128 + 64 + m * 16 + l15;                                 \
      a1[m][0] = fragld(Ac, row, coff0);                                      \
      a1[m][1] = fragld(Ac, row, coff1);                                      \
    }                                                                         \
    stage(aS, An, 0, (KN1E));                                                 \
    stage(aS, An, 1, (KN1E));                                                 \
    stage(aS, An, 2, (KN1E));                                                 \
    stage(aS, An, 3, (KN1E));                                                 \
    asm volatile("s_waitcnt lgkmcnt(8)" ::: "memory");  /* a0 done */         \
    __builtin_amdgcn_sched_barrier(0);                                        \
    __builtin_amdgcn_s_setprio(1);                                            \
    CLUSTER(0, a0)                                                            \
    __builtin_amdgcn_s_setprio(0);                                            \
    asm volatile("s_waitcnt lgkmcnt(0)" ::: "memory");  /* a1 done */         \
    __builtin_amdgcn_sched_barrier(0);                                        \
    __builtin_amdgcn_s_setprio(1);                                            \
    CLUSTER(4, a1)                                                            \
    __builtin_amdgcn_s_setprio(0);                                            \
    asm volatile("s_waitcnt vmcnt(0)" ::: "memory");  /* stages(u+1) done */  \
    __builtin_amdgcn_s_barrier();                                             \
  }

#pragma unroll 1
  for (int u = 0; u < NKT; u += 2) {
    const int k1 = (u + 1 < NKT) ? (u + 1) : (NKT - 1);
    const int k2 = (u + 2 < NKT) ? (u + 2) : (NKT - 1);
    KITER(lds + 0,     lds + 16384, u,     k1 * 64);
    KITER(lds + 16384, lds + 0,     u + 1, k2 * 64);
  }
#undef KITER
#undef CLUSTER

  // ---- epilogue: C/D layout col=lane&15, row=(lane>>4)*4+r
#pragma unroll
  for (int n = 0; n < 4; ++n) {
    int col = tile_n * 256 + wcn * 64 + n * 16 + l15;
    float bv = bias[col];
#pragma unroll
    for (int m = 0; m < 8; ++m) {
      int row0 = tile_m * 256 + wr * 128 + m * 16 + ((lane >> 4) * 4);
#pragma unroll
      for (int r = 0; r < 4; ++r) {
        C[(size_t)(row0 + r) * NT + col] = acc[m][n][r] + bv;
      }
    }
  }
}

// ============ fallback path: no workspace, fp32 sources, reg convert ========
__global__ void gemm_fused_f32_kernel(const float* __restrict__ x,
                                      const float* __restrict__ w4,
                                      const float* __restrict__ w8,
                                      const int* __restrict__ inv_perm,
                                      const float* __restrict__ bias,
                                      float* __restrict__ C) {
  __shared__ __align__(16) unsigned short Alds[128 * 64];
  __shared__ __align__(16) unsigned short Blds[128 * 64];

  int bid = blockIdx.x;
  int wgid = (bid & 7) * ((M_DIM / 128) * (NT / 128) / 8) + (bid >> 3);
  int tile_n = wgid % (NT / 128);
  int tile_m = wgid / (NT / 128);

  const int tid  = threadIdx.x;
  const int wid  = tid >> 6;
  const int lane = tid & 63;
  const int wr = wid >> 1, wc = wid & 1;

  f32x4 acc[4][4];
#pragma unroll
  for (int i = 0; i < 4; ++i)
#pragma unroll
    for (int j = 0; j < 4; ++j) acc[i][j] = (f32x4){0.f, 0.f, 0.f, 0.f};

  const int lrow = lane >> 3;
  const int lcol = (lane & 7) * 8;

  const float* asrc[4];
  const float* bsrc[4];
  int ldsoff[4];
#pragma unroll
  for (int s = 0; s < 4; ++s) {
    int rb = s * 32 + wid * 8 + lrow;
    asrc[s] = x + (size_t)(tile_m * 128 + rb) * K_DIM + lcol;
    int c = inv_perm[tile_n * 128 + rb];
    bsrc[s] = ((c < N4) ? (w4 + (size_t)c * K_DIM)
                        : (w8 + (size_t)(c - N4) * K_DIM)) + lcol;
    ldsoff[s] = rb * 64 + lcol;
  }

  for (int kt = 0; kt < K_DIM; kt += 64) {
#pragma unroll
    for (int s = 0; s < 4; ++s) {
      float4v a0 = *(const float4v*)(asrc[s] + kt);
      float4v a1 = *(const float4v*)(asrc[s] + kt + 4);
      float4v b0 = *(const float4v*)(bsrc[s] + kt);
      float4v b1 = *(const float4v*)(bsrc[s] + kt + 4);
      ushort8v oa, ob;
      oa[0]=f2bf(a0[0]); oa[1]=f2bf(a0[1]); oa[2]=f2bf(a0[2]); oa[3]=f2bf(a0[3]);
      oa[4]=f2bf(a1[0]); oa[5]=f2bf(a1[1]); oa[6]=f2bf(a1[2]); oa[7]=f2bf(a1[3]);
      ob[0]=f2bf(b0[0]); ob[1]=f2bf(b0[1]); ob[2]=f2bf(b0[2]); ob[3]=f2bf(b0[3]);
      ob[4]=f2bf(b1[0]); ob[5]=f2bf(b1[1]); ob[6]=f2bf(b1[2]); ob[7]=f2bf(b1[3]);
      *(ushort8v*)&Alds[ldsoff[s]] = oa;
      *(ushort8v*)&Blds[ldsoff[s]] = ob;
    }
    __syncthreads();

#pragma unroll
    for (int kk = 0; kk < 2; ++kk) {
      bf16x8 af[4], bfr[4];
#pragma unroll
      for (int i = 0; i < 4; ++i) {
        int row = wr * 64 + i * 16 + (lane & 15);
        af[i] = *(const bf16x8*)&Alds[row * 64 + kk * 32 + (lane >> 4) * 8];
      }
#pragma unroll
      for (int j = 0; j < 4; ++j) {
        int row = wc * 64 + j * 16 + (lane & 15);
        bfr[j] = *(const bf16x8*)&Blds[row * 64 + kk * 32 + (lane >> 4) * 8];
      }
#pragma unroll
      for (int i = 0; i < 4; ++i)
#pragma unroll
        for (int j = 0; j < 4; ++j)
          acc[i][j] = __builtin_amdgcn_mfma_f32_16x16x32_bf16(af[i], bfr[j], acc[i][j], 0, 0, 0);
    }
    __syncthreads();
  }

#pragma unroll
  for (int j = 0; j < 4; ++j) {
    int col = tile_n * 128 + wc * 64 + j * 16 + (lane & 15);
    float bv = bias[col];
#pragma unroll
    for (int i = 0; i < 4; ++i) {
      int row0 = tile_m * 128 + wr * 64 + i * 16 + ((lane >> 4) * 4);
#pragma unroll
      for (int r = 0; r < 4; ++r) {
        C[(size_t)(row0 + r) * NT + col] = acc[i][j][r] + bv;
      }
    }
  }
}

extern "C" void kernel_launch(void* const* d_in, const int* in_sizes, int n_in,
                              void* d_out, int out_size, void* d_ws, size_t ws_size,
                              hipStream_t stream) {
  const float* x    = (const float*)d_in[0];
  const float* w4   = (const float*)d_in[1];
  const float* w8   = (const float*)d_in[2];
  const int*   perm = (const int*)d_in[3];
  const float* bias = (const float*)d_in[4];
  float*       out  = (float*)d_out;

  const size_t xb_bytes = (size_t)M_DIM * K_DIM * 2;
  const size_t wb_bytes = (size_t)NT * K_DIM * 2;

  if (ws_size >= xb_bytes + wb_bytes) {
    unsigned short* xb = (unsigned short*)d_ws;
    unsigned short* w2 = xb + (size_t)M_DIM * K_DIM;
    conv_x_kernel<<<2048, 256, 0, stream>>>(x, xb, (M_DIM * K_DIM) / 8);
    conv_w2_kernel<<<2752, 256, 0, stream>>>(w4, w8, perm, w2);
    gemm256_kernel<<<GRID, 512, 0, stream>>>(xb, w2, bias, out);
  } else {
    int grid = (M_DIM / 128) * (NT / 128);
    gemm_fused_f32_kernel<<<grid, 256, 0, stream>>>(x, w4, w8, perm, bias, out);
  }
}